// Round 13
// baseline (251.408 us; speedup 1.0000x reference)
//
#include <hip/hip_runtime.h>

typedef __bf16 bf8 __attribute__((ext_vector_type(8)));
typedef float f4 __attribute__((ext_vector_type(4)));
typedef unsigned short us4 __attribute__((ext_vector_type(4)));
typedef unsigned int u32x4 __attribute__((ext_vector_type(4)));

#define MFMA16(a,b,c) __builtin_amdgcn_mfma_f32_16x16x32_bf16((a),(b),(c),0,0,0)

#define BLOCK 512
#define NWAVE 8
#define HBLOCK 512
#define CH 16384

__device__ __forceinline__ unsigned short f2bfu(float f){
  __bf16 h = (__bf16)f;
  union { __bf16 b; unsigned short u; } v; v.b = h; return v.u;
}
__device__ __forceinline__ float ubfu(unsigned int u16){
  union { unsigned int i; float f; } v; v.i = u16 << 16; return v.f;
}
__device__ __forceinline__ float u2f(unsigned int u){
  union { unsigned int i; float f; } v; v.i = u; return v.f;
}

// Wave-local LDS fence (validated rounds 4-12; act buffers wave-private).
__device__ __forceinline__ void wfence(){
  asm volatile("s_waitcnt lgkmcnt(0)" ::: "memory");
}

// LDS layout (ushort element offsets). W3C = w3@cw1 fused color-layer-1.
#define OFF_W1   0       // 32->64 : 2048
#define OFF_W2   2048    // 64->64 : 4096
#define OFF_W3C  6144    // 64->64 fused : 4096
#define OFF_CW2  10240
#define OFF_CW3  14336
#define OFF_CW4  18432   // 64->3 zero-padded : 1024
#define OFF_W3C0 19456   // w3 column 0 : 72
#define OFF_ACT  19528
#define ACT_STRIDE 72
// 2 tiles per wave -> 32 act rows per wave
#define SMEM_US  (19528 + NWAVE*32*ACT_STRIDE)  // 37960 shorts = 75920 B (2 blocks/CU)

// bias offsets (bf16 shorts)
#define NB_B1  0
#define NB_B2  64
#define NB_BC  128
#define NB_CB2 192
#define NB_CB3 256
#define NB_CB4 320
#define NB_B3S 323

template<int FIN,int FOUT,int KS,int MT>
__device__ __forceinline__ void stage_w(const float* w, unsigned short* dst){
  const int total = KS*MT*512;
  for (int e = threadIdx.x; e < total; e += BLOCK){
    int chunk = e >> 9;
    int s = chunk / MT, t = chunk % MT;
    int le = e & 511;
    int lane = le >> 3, j = le & 7;
    int q = lane >> 4, m = lane & 15;
    int i = s*32 + q*8 + j;
    int o = t*16 + m;
    dst[e] = (i < FIN && o < FOUT) ? f2bfu(w[i*FOUT + o]) : (unsigned short)0;
  }
}

// W3C = w3@cw1 computed inline during staging (fp32 math, bf16 store).
__device__ __forceinline__ void stage_w3c_inline(const float* w3, const float* cw1,
                                                 unsigned short* dst){
  for (int e = threadIdx.x; e < 4096; e += BLOCK){
    int chunk = e >> 9;
    int s = chunk >> 2, t = chunk & 3;
    int le = e & 511;
    int lane = le >> 3, j = le & 7;
    int q = lane >> 4, m = lane & 15;
    int i = s*32 + q*8 + j;
    int o = t*16 + m;
    float sum = 0.f;
#pragma unroll
    for (int u = 0; u < 16; ++u) sum = fmaf(w3[i*16+u], cw1[u*64+o], sum);
    dst[e] = f2bfu(sum);
  }
}

// 64->64 layer, bias in accumulator init.
__device__ __forceinline__ void layer64b(const unsigned short* wlds, const unsigned short* bias,
                                         unsigned short* act, int lane, bool relu){
  const int q = lane >> 4, m = lane & 15;
  bf8 b0 = *(const bf8*)(act + m*ACT_STRIDE + q*8);
  bf8 b1 = *(const bf8*)(act + m*ACT_STRIDE + 32 + q*8);
  f4 acc[4];
#pragma unroll
  for (int t = 0; t < 4; ++t){
    us4 bb = *(const us4*)(bias + t*16 + q*4);
    f4 c = {ubfu(bb[0]), ubfu(bb[1]), ubfu(bb[2]), ubfu(bb[3])};
    c = MFMA16(*(const bf8*)(wlds + ((0*4+t)*64+lane)*8), b0, c);
    c = MFMA16(*(const bf8*)(wlds + ((1*4+t)*64+lane)*8), b1, c);
    acc[t] = c;
  }
#pragma unroll
  for (int t = 0; t < 4; ++t){
    us4 pk;
#pragma unroll
    for (int r = 0; r < 4; ++r){
      float v = relu ? fmaxf(acc[t][r], 0.f) : acc[t][r];
      pk[r] = f2bfu(v);
    }
    *(us4*)(act + m*ACT_STRIDE + t*16 + q*4) = pk;
  }
}

#define STAGE_COMMON()                                                       \
  stage_w<32,64,1,4>(w1,  smem+OFF_W1);                                      \
  stage_w<64,64,2,4>(w2,  smem+OFF_W2);                                      \
  stage_w<64,64,2,4>(cw2, smem+OFF_CW2);                                     \
  stage_w<64,64,2,4>(cw3, smem+OFF_CW3);                                     \
  stage_w<64, 3,2,1>(cw4, smem+OFF_CW4);                                     \
  stage_w3c_inline(w3, cw1, smem+OFF_W3C);                                   \
  {                                                                          \
    int t = threadIdx.x;                                                     \
    if (t < 64){                                                             \
      sbias[NB_B1 +t] = f2bfu(b1[t]);                                        \
      sbias[NB_B2 +t] = f2bfu(b2[t]);                                        \
      sbias[NB_CB2+t] = f2bfu(cb2[t]);                                       \
      sbias[NB_CB3+t] = f2bfu(cb3[t]);                                       \
      smem[OFF_W3C0+t] = f2bfu(w3[t*16]);                                    \
      float bcv = cb1[t];                                                    \
      _Pragma("unroll")                                                      \
      for (int j = 0; j < 16; ++j) bcv = fmaf(b3[j], cw1[j*64+t], bcv);      \
      sbias[NB_BC+t] = f2bfu(bcv);                                           \
    }                                                                        \
    if (t >= 64 && t < 72) smem[OFF_W3C0+t] = 0;                             \
    if (t < 3)  sbias[NB_CB4+t] = f2bfu(cb4[t]);                             \
    if (t == 0) sbias[NB_B3S]   = f2bfu(b3[0]);                              \
  }

// L1 (32->64, relu) for one tile from bfrag.
__device__ __forceinline__ void layerL1(const unsigned short* smem, const unsigned short* sbias,
                                        bf8 bfrag, unsigned short* act, int lane){
  const int q = lane >> 4, m = lane & 15;
  f4 acc[4];
#pragma unroll
  for (int t = 0; t < 4; ++t){
    us4 bb = *(const us4*)(sbias + NB_B1 + t*16 + q*4);
    f4 c = {ubfu(bb[0]), ubfu(bb[1]), ubfu(bb[2]), ubfu(bb[3])};
    acc[t] = MFMA16(*(const bf8*)(smem + OFF_W1 + (t*64+lane)*8), bfrag, c);
  }
#pragma unroll
  for (int t = 0; t < 4; ++t){
    us4 pk;
#pragma unroll
    for (int r = 0; r < 4; ++r) pk[r] = f2bfu(fmaxf(acc[t][r], 0.f));
    *(us4*)(act + m*ACT_STRIDE + t*16 + q*4) = pk;
  }
}

// sigma head: d0 = h2 . w3col0 + b3[0], out[gp] = exp(d0). No act write.
__device__ __forceinline__ void sigma_head(const unsigned short* smem, float b3f,
                                           const unsigned short* act, int lane,
                                           float* out, int gp, int nB){
  const int q = lane >> 4, m = lane & 15;
  bf8 a0 = *(const bf8*)(smem + OFF_W3C0 + q*8);
  bf8 a1 = *(const bf8*)(smem + OFF_W3C0 + 32 + q*8);
  bf8 b0 = *(const bf8*)(act + m*ACT_STRIDE + q*8);
  bf8 b1 = *(const bf8*)(act + m*ACT_STRIDE + 32 + q*8);
  f4 c = {b3f, b3f, b3f, b3f};
  c = MFMA16(a0, b0, c);
  c = MFMA16(a1, b1, c);
  if (q == 0 && gp < nB) out[gp] = expf(c[0]);
}

// C4 head: 64->3 + sigmoid.
__device__ __forceinline__ void c4_head(const unsigned short* smem, const unsigned short* sbias,
                                        const unsigned short* act, int lane,
                                        float* out, int gp, int nB){
  const int q = lane >> 4, m = lane & 15;
  bf8 b0 = *(const bf8*)(act + m*ACT_STRIDE + q*8);
  bf8 b1 = *(const bf8*)(act + m*ACT_STRIDE + 32 + q*8);
  f4 c = {0.f,0.f,0.f,0.f};
  c = MFMA16(*(const bf8*)(smem + OFF_CW4 + lane*8), b0, c);
  c = MFMA16(*(const bf8*)(smem + OFF_CW4 + (64+lane)*8), b1, c);
  if (q == 0 && gp < nB){
#pragma unroll
    for (int r = 0; r < 3; ++r){
      float v = c[r] + ubfu(sbias[NB_CB4 + r]);
      out[nB + gp*3 + r] = 1.f/(1.f + expf(-v));
    }
  }
}

// ---------------------------------------------------------------------------
// Phase A: per-level hash encode, full table in LDS (512 threads — r9-proven).
// ---------------------------------------------------------------------------
__global__ __launch_bounds__(HBLOCK) void hash_phase(
    const float* __restrict__ xin, const float* __restrict__ tab,
    unsigned int* __restrict__ feat, int nB)
{
  __shared__ unsigned int stab[16384];
  __shared__ int sres[16];
  const int lvl = blockIdx.y;
  {
    const float2* t2 = (const float2*)tab + (lvl<<14);
    for (int e = threadIdx.x; e < 16384; e += HBLOCK){
      float2 v = t2[e];
      stab[e] = ((unsigned)f2bfu(v.y) << 16) | (unsigned)f2bfu(v.x);
    }
    if (threadIdx.x < 16){
      const int R[16] = {16,20,25,32,40,50,64,80,101,128,161,203,256,322,406,512};
      sres[threadIdx.x] = R[threadIdx.x];
    }
  }
  __syncthreads();

  const int res = sres[lvl];
  const float sc = 0.5f*(float)(res-1);
  const bool dense = (lvl < 3);
  unsigned int* fout = feat + (size_t)lvl * (size_t)nB;

  int pend = (blockIdx.x + 1) * CH; if (pend > nB) pend = nB;
  for (int p = blockIdx.x*CH + threadIdx.x; p < pend; p += HBLOCK){
    const float px = xin[p*3+0], py = xin[p*3+1], pz = xin[p*3+2];
    const float xs=(px+1.f)*sc, ys=(py+1.f)*sc, zs=(pz+1.f)*sc;
    const float fx=floorf(xs), fy=floorf(ys), fz=floorf(zs);
    const float wx=xs-fx, wy=ys-fy, wz=zs-fz;
    int ix0=min(max((int)fx,0),res-1);
    int iy0=min(max((int)fy,0),res-1);
    int iz0=min(max((int)fz,0),res-1);
    int ix1=min(ix0+1,res-1), iy1=min(iy0+1,res-1), iz1=min(iz0+1,res-1);
    unsigned X0,X1,Y0,Y1,Z0,Z1;
    if (dense){
      X0=(unsigned)ix0;            X1=(unsigned)ix1;
      Y0=(unsigned)(res*iy0);      Y1=(unsigned)(res*iy1);
      Z0=(unsigned)(res*res*iz0);  Z1=(unsigned)(res*res*iz1);
    } else {
      X0=(unsigned)ix0;                 X1=(unsigned)ix1;
      Y0=(unsigned)iy0*2654435761u;     Y1=(unsigned)iy1*2654435761u;
      Z0=(unsigned)iz0*805459861u;      Z1=(unsigned)iz1*805459861u;
    }
    const float wx0=1.f-wx, wy0=1.f-wy, wz0=1.f-wz;
    const float wxy0=wx0*wy0, wxy1=wx*wy0, wxy2=wx0*wy, wxy3=wx*wy;
    float f0=0.f, f1=0.f;
#pragma unroll
    for (int c = 0; c < 8; ++c){
      unsigned xc = (c&1)?X1:X0;
      unsigned yc = (c&2)?Y1:Y0;
      unsigned zc = (c&4)?Z1:Z0;
      unsigned idx = dense ? (xc+yc+zc) : ((xc^yc^zc)&16383u);
      unsigned tv = stab[idx];
      float wxy = (c&2) ? ((c&1)?wxy3:wxy2) : ((c&1)?wxy1:wxy0);
      float wc  = wxy * ((c&4)?wz:wz0);
      f0 = fmaf(wc, u2f(tv << 16), f0);
      f1 = fmaf(wc, u2f(tv & 0xffff0000u), f1);
    }
    fout[p] = ((unsigned)f2bfu(f1) << 16) | (unsigned)f2bfu(f0);
  }
}

// ---------------------------------------------------------------------------
// Phase B: MLP, TWO independent 16-point tiles per fence window (2x ILP in
// the latency chain — r12 showed the chain, not inst count, is the limit).
// ---------------------------------------------------------------------------
__global__ __launch_bounds__(BLOCK) void mlp_phase(
    const unsigned int* __restrict__ feat,
    const float* __restrict__ w1,  const float* __restrict__ b1,
    const float* __restrict__ w2,  const float* __restrict__ b2,
    const float* __restrict__ w3,  const float* __restrict__ b3,
    const float* __restrict__ cw1, const float* __restrict__ cb1,
    const float* __restrict__ cw2, const float* __restrict__ cb2,
    const float* __restrict__ cw3, const float* __restrict__ cb3,
    const float* __restrict__ cw4, const float* __restrict__ cb4,
    float* __restrict__ out, int nB)
{
  __shared__ __align__(16) unsigned short smem[SMEM_US];
  __shared__ __align__(16) unsigned short sbias[328];
  STAGE_COMMON();
  __syncthreads();

  const int lane = threadIdx.x & 63, wv = threadIdx.x >> 6;
  const int q = lane >> 4, m = lane & 15;
  unsigned short* act0 = smem + OFF_ACT + wv*32*ACT_STRIDE;
  unsigned short* act1 = act0 + 16*ACT_STRIDE;
  const unsigned int* fq = feat + (size_t)(4*q) * (size_t)nB;
  const float b3f = ubfu(sbias[NB_B3S]);

  for (int it = 0; it < 2; ++it){
    const int gp0 = blockIdx.x*BLOCK + wv*64 + it*32 + m;
    const int gp1 = gp0 + 16;
    const int gl0 = min(gp0, nB-1), gl1 = min(gp1, nB-1);
    union { u32x4 u; bf8 b; } fb0, fb1;
    fb0.u[0] = fq[gl0];                    fb1.u[0] = fq[gl1];
    fb0.u[1] = fq[(size_t)nB   + gl0];     fb1.u[1] = fq[(size_t)nB   + gl1];
    fb0.u[2] = fq[(size_t)nB*2 + gl0];     fb1.u[2] = fq[(size_t)nB*2 + gl1];
    fb0.u[3] = fq[(size_t)nB*3 + gl0];     fb1.u[3] = fq[(size_t)nB*3 + gl1];

    layerL1(smem, sbias, fb0.b, act0, lane);
    layerL1(smem, sbias, fb1.b, act1, lane);
    wfence();
    layer64b(smem+OFF_W2, sbias+NB_B2, act0, lane, true);
    layer64b(smem+OFF_W2, sbias+NB_B2, act1, lane, true);
    wfence();
    sigma_head(smem, b3f, act0, lane, out, gp0, nB);
    sigma_head(smem, b3f, act1, lane, out, gp1, nB);
    layer64b(smem+OFF_W3C, sbias+NB_BC, act0, lane, true);
    layer64b(smem+OFF_W3C, sbias+NB_BC, act1, lane, true);
    wfence();
    layer64b(smem+OFF_CW2, sbias+NB_CB2, act0, lane, true);
    layer64b(smem+OFF_CW2, sbias+NB_CB2, act1, lane, true);
    wfence();
    layer64b(smem+OFF_CW3, sbias+NB_CB3, act0, lane, true);
    layer64b(smem+OFF_CW3, sbias+NB_CB3, act1, lane, true);
    wfence();
    c4_head(smem, sbias, act0, lane, out, gp0, nB);
    c4_head(smem, sbias, act1, lane, out, gp1, nB);
    wfence();
  }
}

// ---------------------------------------------------------------------------
// Fallback (workspace too small): fused hash+MLP, single tile per iter.
// ---------------------------------------------------------------------------
__global__ __launch_bounds__(BLOCK) void nerf_fused(
    const float* __restrict__ xin, const float* __restrict__ tab,
    const float* __restrict__ w1,  const float* __restrict__ b1,
    const float* __restrict__ w2,  const float* __restrict__ b2,
    const float* __restrict__ w3,  const float* __restrict__ b3,
    const float* __restrict__ cw1, const float* __restrict__ cb1,
    const float* __restrict__ cw2, const float* __restrict__ cb2,
    const float* __restrict__ cw3, const float* __restrict__ cb3,
    const float* __restrict__ cw4, const float* __restrict__ cb4,
    float* __restrict__ out, int nB)
{
  __shared__ __align__(16) unsigned short smem[SMEM_US];
  __shared__ __align__(16) unsigned short sbias[328];
  __shared__ int sres[16];
  STAGE_COMMON();
  if (threadIdx.x < 16){
    const int R[16] = {16,20,25,32,40,50,64,80,101,128,161,203,256,322,406,512};
    sres[threadIdx.x] = R[threadIdx.x];
  }
  __syncthreads();

  const int lane = threadIdx.x & 63, wv = threadIdx.x >> 6;
  const int q = lane >> 4, m = lane & 15;
  unsigned short* act = smem + OFF_ACT + wv*32*ACT_STRIDE;
  const float b3f = ubfu(sbias[NB_B3S]);

  int res_[4];
#pragma unroll
  for (int d = 0; d < 4; ++d) res_[d] = sres[4*q + d];

  for (int it = 0; it < 4; ++it){
    const int gp  = blockIdx.x*BLOCK + wv*64 + it*16 + m;
    const int gpl = min(gp, nB-1);
    const float px = xin[gpl*3+0];
    const float py = xin[gpl*3+1];
    const float pz = xin[gpl*3+2];

    bf8 bfrag;
#pragma unroll
    for (int d = 0; d < 4; ++d){
      const int lvl = 4*q + d;
      const int res = res_[d];
      const float sc = 0.5f*(float)(res-1);
      const float xs=(px+1.f)*sc, ys=(py+1.f)*sc, zs=(pz+1.f)*sc;
      const float fx=floorf(xs), fy=floorf(ys), fz=floorf(zs);
      const float wx=xs-fx, wy=ys-fy, wz=zs-fz;
      int ix0=min(max((int)fx,0),res-1);
      int iy0=min(max((int)fy,0),res-1);
      int iz0=min(max((int)fz,0),res-1);
      int ix1=min(ix0+1,res-1), iy1=min(iy0+1,res-1), iz1=min(iz0+1,res-1);
      const bool dense = (lvl < 3);
      unsigned X0,X1,Y0,Y1,Z0,Z1;
      if (dense){
        X0=(unsigned)ix0;            X1=(unsigned)ix1;
        Y0=(unsigned)(res*iy0);      Y1=(unsigned)(res*iy1);
        Z0=(unsigned)(res*res*iz0);  Z1=(unsigned)(res*res*iz1);
      } else {
        X0=(unsigned)ix0;                 X1=(unsigned)ix1;
        Y0=(unsigned)iy0*2654435761u;     Y1=(unsigned)iy1*2654435761u;
        Z0=(unsigned)iz0*805459861u;      Z1=(unsigned)iz1*805459861u;
      }
      const float wx0=1.f-wx, wy0=1.f-wy, wz0=1.f-wz;
      float f0=0.f, f1=0.f;
      const float2* tl = (const float2*)tab + (lvl<<14);
#pragma unroll
      for (int c = 0; c < 8; ++c){
        unsigned xc = (c&1)?X1:X0;
        unsigned yc = (c&2)?Y1:Y0;
        unsigned zc = (c&4)?Z1:Z0;
        unsigned idx = dense ? (xc+yc+zc) : ((xc^yc^zc)&16383u);
        float2 tv = tl[idx];
        float wc = ((c&1)?wx:wx0) * ((c&2)?wy:wy0) * ((c&4)?wz:wz0);
        f0 += wc*tv.x;
        f1 += wc*tv.y;
      }
      bfrag[2*d]   = (__bf16)f0;
      bfrag[2*d+1] = (__bf16)f1;
    }

    layerL1(smem, sbias, bfrag, act, lane);
    wfence();
    layer64b(smem+OFF_W2, sbias+NB_B2, act, lane, true);
    wfence();
    sigma_head(smem, b3f, act, lane, out, gp, nB);
    layer64b(smem+OFF_W3C, sbias+NB_BC, act, lane, true);
    wfence();
    layer64b(smem+OFF_CW2, sbias+NB_CB2, act, lane, true);
    wfence();
    layer64b(smem+OFF_CW3, sbias+NB_CB3, act, lane, true);
    wfence();
    c4_head(smem, sbias, act, lane, out, gp, nB);
    wfence();
  }
}

extern "C" void kernel_launch(void* const* d_in, const int* in_sizes, int n_in,
                              void* d_out, int out_size, void* d_ws, size_t ws_size,
                              hipStream_t stream) {
  (void)n_in; (void)out_size;
  const int nB = in_sizes[0] / 3;
  const float* xin = (const float*)d_in[0];
  const float* tab = (const float*)d_in[1];
  const float *w1=(const float*)d_in[2],  *b1=(const float*)d_in[3];
  const float *w2=(const float*)d_in[4],  *b2=(const float*)d_in[5];
  const float *w3=(const float*)d_in[6],  *b3=(const float*)d_in[7];
  const float *cw1=(const float*)d_in[8], *cb1=(const float*)d_in[9];
  const float *cw2=(const float*)d_in[10],*cb2=(const float*)d_in[11];
  const float *cw3=(const float*)d_in[12],*cb3=(const float*)d_in[13];
  const float *cw4=(const float*)d_in[14],*cb4=(const float*)d_in[15];
  float* out = (float*)d_out;

  const size_t need = (size_t)nB * 16u * 4u;
  if (ws_size >= need){
    unsigned int* feat = (unsigned int*)d_ws;
    dim3 ga((nB + CH - 1) / CH, 16);
    hash_phase<<<ga, dim3(HBLOCK), 0, stream>>>(xin, tab, feat, nB);
    const int blocks = (nB + BLOCK - 1) / BLOCK;
    mlp_phase<<<dim3(blocks), dim3(BLOCK), 0, stream>>>(
        feat, w1,b1,w2,b2,w3,b3,
        cw1,cb1,cw2,cb2,cw3,cb3,cw4,cb4, out, nB);
  } else {
    const int blocks = (nB + BLOCK - 1) / BLOCK;
    nerf_fused<<<dim3(blocks), dim3(BLOCK), 0, stream>>>(
        xin, tab, w1,b1,w2,b2,w3,b3,
        cw1,cb1,cw2,cb2,cw3,cb3,cw4,cb4, out, nB);
  }
}